// Round 11
// baseline (370.722 us; speedup 1.0000x reference)
//
#include <hip/hip_runtime.h>
#include <hip/hip_fp16.h>
#include <math.h>

#define NN 512
#define NODE_D 256
#define EDGE_D 128
#define HN 8

#define SCALAR_SCALE 0.14433756729740643f   // (3*16)^-0.5
#define POINT_SCALE  0.13608276348795434f   // (3*4*4.5)^-0.5
#define PAIR_SCALE   0.5773502691896258f    // 3^-0.5

// workspace float offsets
#define OFF_QS   0            // 512x128
#define OFF_KS   65536        // 512x128
#define OFF_VS   131072       // 512x128
#define OFF_VP   196608       // 512x96
#define OFF_QCAT 245760       // 512x288
#define OFF_KCAT 393216       // 512x288
#define OFF_FEAT 540672       // 512x1280
#define OFF_PRAW OFF_FEAT     // alias; consumed by k_rot2 before feat written
#define OFF_LG16 1196032      // 512*512*8 halfs = 1048576 float-equiv (4MB)
#define OFF_OUTP 2244608      // 4*512*256 floats
#define OFF_PART 2768896      // 512 i x 2 jc x 1280 floats (5.2MB)
// total ws = 4079616 floats = 16.3 MB

// Non-draining barrier: orders LDS producer->consumer (lgkmcnt) WITHOUT
// draining vmcnt — keeps global prefetch loads in flight across phases.
// Single asm block so nothing is scheduled between wait and barrier;
// "memory" clobber + sched_barrier(0) fence compiler/scheduler movement.
#define BARRIER_NODRAIN() do {                                   \
  __builtin_amdgcn_sched_barrier(0);                             \
  asm volatile("s_waitcnt lgkmcnt(0)\n\ts_barrier" ::: "memory");\
  __builtin_amdgcn_sched_barrier(0);                             \
} while (0)

// ---------------------------------------------------------------------------
// Kernel A1: Y(512x672) = node @ [Wsq|Wsk|Wsv|Wpq|Wpk|Wpv]. grid (16,21).
// ---------------------------------------------------------------------------
__global__ __launch_bounds__(256) void k_projgemm(
    const float* __restrict__ node,
    const float* __restrict__ Wsq, const float* __restrict__ Wsk, const float* __restrict__ Wsv,
    const float* __restrict__ Wpq, const float* __restrict__ Wpk, const float* __restrict__ Wpv,
    float* __restrict__ ws)
{
  __shared__ float As[32 * 33];
  __shared__ float Bs[32 * 36];
  const int t = threadIdx.x;
  const int it = blockIdx.x;
  const int ct = blockIdx.y;

  const float* W; int ncol, col0; float* dst; int ldd, dcol0;
  if (ct < 12) {
    int a = ct >> 2;
    W = (a == 0) ? Wsq : (a == 1) ? Wsk : Wsv;
    ncol = 128; col0 = (ct & 3) * 32;
    dst = ws + ((a == 0) ? OFF_QS : (a == 1) ? OFF_KS : OFF_VS);
    ldd = 128; dcol0 = col0;
  } else {
    int p = ct - 12;
    int a = p / 3, cc = p % 3;
    W = (a == 0) ? Wpq : (a == 1) ? Wpk : Wpv;
    ncol = 96; col0 = cc * 32;
    dst = ws + OFF_PRAW;
    ldd = 288; dcol0 = a * 96 + cc * 32;
  }

  const int row = t & 31, cb = (t >> 5) * 4;
  float4 acc = {0.f, 0.f, 0.f, 0.f};

  for (int kt = 0; kt < 8; ++kt) {
    __syncthreads();
    #pragma unroll
    for (int q = 0; q < 4; ++q) {
      int f = t + q * 256; int r = f >> 5, c = f & 31;
      As[r * 33 + c] = node[(size_t)(it * 32 + r) * 256 + kt * 32 + c];
      Bs[r * 36 + c] = W[(size_t)(kt * 32 + r) * ncol + col0 + c];
    }
    __syncthreads();
    #pragma unroll
    for (int k = 0; k < 32; ++k) {
      float a = As[row * 33 + k];
      float4 b = *(const float4*)&Bs[k * 36 + cb];
      acc.x += a * b.x; acc.y += a * b.y; acc.z += a * b.z; acc.w += a * b.w;
    }
  }
  *(float4*)&dst[(size_t)(it * 32 + row) * ldd + dcol0 + cb] = acc;
}

// ---------------------------------------------------------------------------
// Kernel A2: rotate/translate points; build Qcat/Kcat (scales folded); vp out.
// ---------------------------------------------------------------------------
__global__ __launch_bounds__(256) void k_rot2(
    const float* __restrict__ rotm, const float* __restrict__ trans,
    const float* __restrict__ pw_in, const float* __restrict__ bpb,
    float* __restrict__ ws)
{
  __shared__ float p_l[4][288];
  __shared__ float r_l[4][288];
  __shared__ float q2_l[4][8];
  __shared__ float k2_l[4][8];
  __shared__ float pw_l[8];
  __shared__ float bpb_l[8];
  const int t = threadIdx.x;
  const int n0 = blockIdx.x * 4;
  const float* praw = ws + OFF_PRAW;
  const float* qs_g = ws + OFF_QS;
  const float* ks_g = ws + OFF_KS;

  if (t < 8) {
    float x = pw_in[t];
    pw_l[t] = 0.5f * POINT_SCALE * logf(1.0f + expf(x));
    bpb_l[t] = bpb[t];
  }
  for (int idx = t; idx < 1152; idx += 256) {
    int row = idx / 288, rem = idx % 288;
    p_l[row][rem] = praw[(size_t)(n0 + row) * 288 + rem];
  }
  __syncthreads();

  for (int idx = t; idx < 1152; idx += 256) {
    int row = idx / 288, rem = idx % 288;
    int a = rem / 96, col = rem % 96;
    int rr = col % 3;
    int n = n0 + row;
    const float* R = rotm + (size_t)(n * 3 + rr) * 3;
    const float* P = &p_l[row][a * 96 + (col - rr)];
    float val = P[0] * R[0] + P[1] * R[1] + P[2] * R[2] + trans[n * 3 + rr];
    r_l[row][a * 96 + col] = val;
    if (a == 2) (ws + OFF_VP)[(size_t)n * 96 + col] = val;
  }
  __syncthreads();

  if (t < 64) {
    int row = t >> 4, rem = t & 15;
    int which = rem >> 3, h = rem & 7;
    const float* src = &r_l[row][which * 96 + h * 12];
    float s = 0.f;
    #pragma unroll
    for (int m = 0; m < 12; ++m) s += src[m] * src[m];
    if (which == 0) q2_l[row][h] = s; else k2_l[row][h] = s;
  }
  __syncthreads();

  for (int idx = t; idx < 2304; idx += 256) {
    int side = idx >= 1152;
    int per = idx - side * 1152;
    int row = per / 288, s = per % 288;
    int h = s / 36, e = s % 36;
    int n = n0 + row;
    float val;
    if (!side) {
      val = (e < 16) ? qs_g[(size_t)n * 128 + h * 16 + e] * SCALAR_SCALE
          : (e < 28) ? 2.0f * pw_l[h] * r_l[row][h * 12 + (e - 16)]
          : (e == 32) ? -pw_l[h]
          : (e == 33) ? (bpb_l[h] * PAIR_SCALE - pw_l[h] * q2_l[row][h])
          : 0.f;
      (ws + OFF_QCAT)[(size_t)n * 288 + s] = val;
    } else {
      val = (e < 16) ? ks_g[(size_t)n * 128 + h * 16 + e]
          : (e < 28) ? r_l[row][96 + h * 12 + (e - 16)]
          : (e == 32) ? k2_l[row][h]
          : (e == 33) ? 1.f
          : 0.f;
      (ws + OFF_KCAT)[(size_t)n * 288 + s] = val;
    }
  }
}

// ---------------------------------------------------------------------------
// Kernel B1: non-pair logits = batched GEMM lg[i,j,h] = dot36(Qcat,Kcat).
// ---------------------------------------------------------------------------
__global__ __launch_bounds__(256) void k_S(
    const float* __restrict__ ws_c, __half* __restrict__ lg16)
{
  __shared__ float4 Qt[32 * 36];
  __shared__ float4 Kt[32 * 37];
  __shared__ __half lgst[32 * 32 * 8];
  const int t = threadIdx.x;
  const int it = blockIdx.x, jt = blockIdx.y;
  const float* Qc = ws_c + OFF_QCAT;
  const float* Kc = ws_c + OFF_KCAT;
  const int ti = t >> 4, tj = t & 15;

  for (int hg = 0; hg < 2; ++hg) {
    __syncthreads();
    for (int f = t; f < 1152; f += 256) {
      int row = f / 36, c = f % 36;
      Qt[row * 36 + c] = *(const float4*)&Qc[(size_t)(it * 32 + row) * 288 + hg * 144 + c * 4];
      Kt[row * 37 + c] = *(const float4*)&Kc[(size_t)(jt * 32 + row) * 288 + hg * 144 + c * 4];
    }
    __syncthreads();

    float acc[2][2][4];
    #pragma unroll
    for (int a = 0; a < 2; ++a)
      #pragma unroll
      for (int b = 0; b < 2; ++b)
        #pragma unroll
        for (int h = 0; h < 4; ++h) acc[a][b][h] = 0.f;

    for (int c = 0; c < 9; ++c) {
      #pragma unroll
      for (int hh = 0; hh < 4; ++hh) {
        float4 q0 = Qt[(2 * ti + 0) * 36 + hh * 9 + c];
        float4 q1 = Qt[(2 * ti + 1) * 36 + hh * 9 + c];
        float4 k0 = Kt[(2 * tj + 0) * 37 + hh * 9 + c];
        float4 k1 = Kt[(2 * tj + 1) * 37 + hh * 9 + c];
        acc[0][0][hh] += q0.x * k0.x + q0.y * k0.y + q0.z * k0.z + q0.w * k0.w;
        acc[0][1][hh] += q0.x * k1.x + q0.y * k1.y + q0.z * k1.z + q0.w * k1.w;
        acc[1][0][hh] += q1.x * k0.x + q1.y * k0.y + q1.z * k0.z + q1.w * k0.w;
        acc[1][1][hh] += q1.x * k1.x + q1.y * k1.y + q1.z * k1.z + q1.w * k1.w;
      }
    }
    #pragma unroll
    for (int a = 0; a < 2; ++a)
      #pragma unroll
      for (int b = 0; b < 2; ++b)
        #pragma unroll
        for (int hh = 0; hh < 4; ++hh)
          lgst[((2 * ti + a) * 32 + (2 * tj + b)) * 8 + hg * 4 + hh] = __float2half(acc[a][b][hh]);
  }
  __syncthreads();

  for (int f = t; f < 1024; f += 256) {
    int il = f >> 5, jl = f & 31;
    float4 v = *(const float4*)&lgst[(il * 32 + jl) * 8];
    *(float4*)&lg16[((size_t)(it * 32 + il) * 512 + jt * 32 + jl) * 8] = v;
  }
}

// ---------------------------------------------------------------------------
// Kernel B2: flash-style fused attention, j-split. grid (2 jc, 512 i).
// Non-draining barriers keep global prefetch in flight across phases.
// ---------------------------------------------------------------------------
static __device__ inline __half2 shfl_xor_h2(__half2 h, int m) {
  int v = __builtin_bit_cast(int, h);
  v = __shfl_xor(v, m);
  return __builtin_bit_cast(__half2, v);
}

__global__ __launch_bounds__(256, 4) void k_attnfused2(
    const float* __restrict__ edge, const float* __restrict__ ws_r,
    const __half* __restrict__ lg16, const float* __restrict__ Wpb,
    float* __restrict__ part)
{
  __shared__ float e_l[2][32][132];    // 33.8 KB (epilogue reuses as pl[4][8][132])
  __shared__ float w_t2[32][8];        // transposed: [j][h], b128 broadcast reads
  __shared__ __half2 lg_th[32][5];     // phase-L pair logits (half2 x4 used)
  __shared__ float mh[8], sh[8], resc[8];
  __shared__ float vsp[4 * 128];
  __shared__ float vpp[4 * 96];

  const int t = threadIdx.x;
  const int jc = blockIdx.x;           // j-chunk 0/1
  const int i  = blockIdx.y;
  const int dq = t & 31, jg = t >> 5;  // phase A mapping
  const int sub = t & 15;              // phase L mapping
  const int hv = dq >> 2;
  const int hp = (dq < 24) ? (dq / 3) : 0;

  const float* eb  = edge + ((size_t)i * 512 + jc * 256) * 128;
  const float* vsg = ws_r + OFF_VS + (size_t)jc * 256 * 128;
  const float* vpg = ws_r + OFF_VP + (size_t)jc * 256 * 96;
  const __half* lgb = lg16 + ((size_t)i * 512 + jc * 256) * 8;

  // per-thread Wpb slice for d = sub*8 + dd (PAIR_SCALE folded)
  float wv[8][8];
  #pragma unroll
  for (int dd = 0; dd < 8; ++dd)
    #pragma unroll
    for (int h = 0; h < 8; ++h)
      wv[dd][h] = Wpb[(size_t)(sub * 8 + dd) * 8 + h] * PAIR_SCALE;

  if (t < 8) { mh[t] = -1e30f; sh[t] = 0.f; }

  float4 accp[8];
  #pragma unroll
  for (int h = 0; h < 8; ++h) accp[h] = {0.f, 0.f, 0.f, 0.f};
  float4 accv = {0.f, 0.f, 0.f, 0.f};
  float4 accw = {0.f, 0.f, 0.f, 0.f};

  // stage tile 0 (32 rows x 512B, fully coalesced)
  #pragma unroll
  for (int p = 0; p < 4; ++p) {
    int f = p * 256 + t, r = f >> 5, g = f & 31;
    *(float4*)&e_l[0][r][g * 4] = *(const float4*)&eb[(size_t)r * 128 + g * 4];
  }
  __syncthreads();   // tile0 staged (full drain ok once)

  int cur = 0;
  for (int tile = 0; tile < 8; ++tile) {
    // prefetch for phase S FIRST (so its use waits at vmcnt(4), leaving nxt in flight)
    __half lgh = lgb[(size_t)(tile * 32 + (t & 31)) * 8 + (t >> 5)];
    // prefetch next tile into registers (T14); retires under phases L/S/A
    float4 nxt0, nxt1, nxt2, nxt3;
    if (tile < 7) {
      const float* ebn = eb + (size_t)(tile + 1) * 32 * 128;
      { int f = t;       int r = f >> 5, g = f & 31; nxt0 = *(const float4*)&ebn[(size_t)r * 128 + g * 4]; }
      { int f = 256 + t; int r = f >> 5, g = f & 31; nxt1 = *(const float4*)&ebn[(size_t)r * 128 + g * 4]; }
      { int f = 512 + t; int r = f >> 5, g = f & 31; nxt2 = *(const float4*)&ebn[(size_t)r * 128 + g * 4]; }
      { int f = 768 + t; int r = f >> 5, g = f & 31; nxt3 = *(const float4*)&ebn[(size_t)r * 128 + g * 4]; }
    }

    // ---- phase L: pair logits, 2 passes x 16 rows; thread (jrow, sub) ----
    #pragma unroll
    for (int pass = 0; pass < 2; ++pass) {
      const int jrow = (t >> 4) + pass * 16;
      float p8[8] = {0, 0, 0, 0, 0, 0, 0, 0};
      #pragma unroll
      for (int k = 0; k < 2; ++k) {
        float4 e = *(float4*)&e_l[cur][jrow][(sub * 2 + k) * 4];
        #pragma unroll
        for (int h = 0; h < 8; ++h)
          p8[h] += e.x * wv[k * 4 + 0][h] + e.y * wv[k * 4 + 1][h]
                 + e.z * wv[k * 4 + 2][h] + e.w * wv[k * 4 + 3][h];
      }
      // pack to half2, 16-lane butterfly (k_pair's proven scheme)
      __half2 h0 = __floats2half2_rn(p8[0], p8[1]);
      __half2 h1 = __floats2half2_rn(p8[2], p8[3]);
      __half2 h2 = __floats2half2_rn(p8[4], p8[5]);
      __half2 h3 = __floats2half2_rn(p8[6], p8[7]);
      #pragma unroll
      for (int m = 1; m <= 8; m <<= 1) {
        h0 = __hadd2(h0, shfl_xor_h2(h0, m));
        h1 = __hadd2(h1, shfl_xor_h2(h1, m));
        h2 = __hadd2(h2, shfl_xor_h2(h2, m));
        h3 = __hadd2(h3, shfl_xor_h2(h3, m));
      }
      if (sub == 0) {
        lg_th[jrow][0] = h0; lg_th[jrow][1] = h1;
        lg_th[jrow][2] = h2; lg_th[jrow][3] = h3;
      }
    }
    BARRIER_NODRAIN();   // lg_th visible; nxt/lgh loads stay in flight

    // ---- phase S: online softmax, full block (h = t>>5, jS = t&31) ----
    {
      const int hS = t >> 5, jS = t & 31;
      __half2 ph = lg_th[jS][hS >> 1];
      float pv = (hS & 1) ? __high2float(ph) : __low2float(ph);
      float x = pv + __half2float(lgh);
      float mt = x;
      #pragma unroll
      for (int s = 16; s; s >>= 1) mt = fmaxf(mt, __shfl_xor(mt, s));
      float mo = mh[hS];
      float mn = fmaxf(mo, mt);
      float w = __expf(x - mn);
      float sw = w;
      #pragma unroll
      for (int s = 16; s; s >>= 1) sw += __shfl_xor(sw, s);
      w_t2[jS][hS] = w;
      if (jS == 0) {
        float r = __expf(mo - mn);
        resc[hS] = r;
        mh[hS] = mn;
        sh[hS] = sh[hS] * r + sw;
      }
    }
    BARRIER_NODRAIN();   // w_t2/resc/mh/sh visible

    // ---- phase A: rescale + accumulate; thread (dq, jg) owns 4 rows ----
    {
      #pragma unroll
      for (int h = 0; h < 8; ++h) {
        float r = resc[h];
        accp[h].x *= r; accp[h].y *= r; accp[h].z *= r; accp[h].w *= r;
      }
      {
        float rv = resc[hv];
        accv.x *= rv; accv.y *= rv; accv.z *= rv; accv.w *= rv;
      }
      if (dq < 24) {
        float rp = resc[hp];
        accw.x *= rp; accw.y *= rp; accw.z *= rp; accw.w *= rp;
      }
      #pragma unroll
      for (int jj = 0; jj < 4; ++jj) {
        const int j = jg * 4 + jj;
        float4 e = *(float4*)&e_l[cur][j][dq * 4];
        float4 wlo = *(float4*)&w_t2[j][0];   // broadcast b128
        float4 whi = *(float4*)&w_t2[j][4];
        accp[0].x += wlo.x * e.x; accp[0].y += wlo.x * e.y; accp[0].z += wlo.x * e.z; accp[0].w += wlo.x * e.w;
        accp[1].x += wlo.y * e.x; accp[1].y += wlo.y * e.y; accp[1].z += wlo.y * e.z; accp[1].w += wlo.y * e.w;
        accp[2].x += wlo.z * e.x; accp[2].y += wlo.z * e.y; accp[2].z += wlo.z * e.z; accp[2].w += wlo.z * e.w;
        accp[3].x += wlo.w * e.x; accp[3].y += wlo.w * e.y; accp[3].z += wlo.w * e.z; accp[3].w += wlo.w * e.w;
        accp[4].x += whi.x * e.x; accp[4].y += whi.x * e.y; accp[4].z += whi.x * e.z; accp[4].w += whi.x * e.w;
        accp[5].x += whi.y * e.x; accp[5].y += whi.y * e.y; accp[5].z += whi.y * e.z; accp[5].w += whi.y * e.w;
        accp[6].x += whi.z * e.x; accp[6].y += whi.z * e.y; accp[6].z += whi.z * e.z; accp[6].w += whi.z * e.w;
        accp[7].x += whi.w * e.x; accp[7].y += whi.w * e.y; accp[7].z += whi.w * e.z; accp[7].w += whi.w * e.w;

        const int gj = tile * 32 + j;
        float4 v = *(const float4*)&vsg[(size_t)gj * 128 + dq * 4];
        float wvv = w_t2[j][hv];             // direct LDS read (no dyn reg index)
        accv.x += wvv * v.x; accv.y += wvv * v.y;
        accv.z += wvv * v.z; accv.w += wvv * v.w;
        if (dq < 24) {
          float4 pv4 = *(const float4*)&vpg[(size_t)gj * 96 + dq * 4];
          float wpp = w_t2[j][hp];
          accw.x += wpp * pv4.x; accw.y += wpp * pv4.y;
          accw.z += wpp * pv4.z; accw.w += wpp * pv4.w;
        }
      }
    }
    BARRIER_NODRAIN();   // phase-A w_t2 reads done before next phase S rewrite

    if (tile < 7) {
      // compiler inserts vmcnt waits on nxt registers here automatically
      { int f = t;       int r = f >> 5, g = f & 31; *(float4*)&e_l[cur ^ 1][r][g * 4] = nxt0; }
      { int f = 256 + t; int r = f >> 5, g = f & 31; *(float4*)&e_l[cur ^ 1][r][g * 4] = nxt1; }
      { int f = 512 + t; int r = f >> 5, g = f & 31; *(float4*)&e_l[cur ^ 1][r][g * 4] = nxt2; }
      { int f = 768 + t; int r = f >> 5, g = f & 31; *(float4*)&e_l[cur ^ 1][r][g * 4] = nxt3; }
      cur ^= 1;
      BARRIER_NODRAIN(); // new tile visible before next phase L
    }
  }

  // ---- epilogue: combine jg pairs in-wave, reduce 4 waves via LDS ----
  #pragma unroll
  for (int h = 0; h < 8; ++h) {
    accp[h].x += __shfl_xor(accp[h].x, 32);
    accp[h].y += __shfl_xor(accp[h].y, 32);
    accp[h].z += __shfl_xor(accp[h].z, 32);
    accp[h].w += __shfl_xor(accp[h].w, 32);
  }
  accv.x += __shfl_xor(accv.x, 32); accv.y += __shfl_xor(accv.y, 32);
  accv.z += __shfl_xor(accv.z, 32); accv.w += __shfl_xor(accv.w, 32);
  accw.x += __shfl_xor(accw.x, 32); accw.y += __shfl_xor(accw.y, 32);
  accw.z += __shfl_xor(accw.z, 32); accw.w += __shfl_xor(accw.w, 32);

  __syncthreads();   // all e_l reads done before reuse as pl (full drain fine here)

  const int wid = t >> 6;
  float* pl = (float*)e_l;   // reuse as [4][8][132]
  if ((t & 63) < 32) {
    #pragma unroll
    for (int h = 0; h < 8; ++h)
      *(float4*)&pl[(size_t)(wid * 8 + h) * 132 + dq * 4] = accp[h];
    *(float4*)&vsp[wid * 128 + dq * 4] = accv;
    if (dq < 24) *(float4*)&vpp[wid * 96 + dq * 4] = accw;
  }
  __syncthreads();

  float* pp = part + ((size_t)i * 2 + jc) * 1280;
  if (t < 8) { pp[t] = mh[t]; pp[8 + t] = sh[t]; }
  {
    const int h = t >> 5, d4 = (t & 31) * 4;
    float4 s = {0.f, 0.f, 0.f, 0.f};
    #pragma unroll
    for (int q = 0; q < 4; ++q) {
      float4 v = *(float4*)&pl[(size_t)(q * 8 + h) * 132 + d4];
      s.x += v.x; s.y += v.y; s.z += v.z; s.w += v.w;
    }
    *(float4*)&pp[16 + h * 128 + d4] = s;
  }
  if (t < 128)
    pp[1040 + t] = vsp[t] + vsp[128 + t] + vsp[256 + t] + vsp[384 + t];
  if (t < 96)
    pp[1168 + t] = vpp[t] + vpp[96 + t] + vpp[192 + t] + vpp[288 + t];
}

// ---------------------------------------------------------------------------
// Kernel B3: merge the 2 j-chunk partials, normalize, rotation/norm epilogue.
// ---------------------------------------------------------------------------
__global__ __launch_bounds__(256) void k_amerge(
    const float* __restrict__ part, const float* __restrict__ rotm,
    const float* __restrict__ trans, float* __restrict__ feat)
{
  __shared__ float r0s[8], r1s[8], lis[8];
  __shared__ float op_l[96], rp_l[96];
  const int t = threadIdx.x, i = blockIdx.x;
  const float* p0 = part + (size_t)i * 2560;
  const float* p1 = p0 + 1280;

  if (t < 8) {
    float m0 = p0[t], m1 = p1[t];
    float M = fmaxf(m0, m1);
    float r0 = __expf(m0 - M), r1 = __expf(m1 - M);
    float S = p0[8 + t] * r0 + p1[8 + t] * r1;
    r0s[t] = r0; r1s[t] = r1; lis[t] = 1.0f / S;
  }
  __syncthreads();

  float* frow = feat + (size_t)i * 1280;
  {
    const int h = t >> 5, d4 = (t & 31) * 4;
    float4 a = *(const float4*)&p0[16 + h * 128 + d4];
    float4 b = *(const float4*)&p1[16 + h * 128 + d4];
    float r0 = r0s[h], r1 = r1s[h], li = lis[h];
    float4 o;
    o.x = (a.x * r0 + b.x * r1) * li;
    o.y = (a.y * r0 + b.y * r1) * li;
    o.z = (a.z * r0 + b.z * r1) * li;
    o.w = (a.w * r0 + b.w * r1) * li;
    *(float4*)&frow[256 + h * 128 + d4] = o;
  }
  if (t < 128) {
    int h = t >> 4;
    frow[t] = (p0[1040 + t] * r0s[h] + p1[1040 + t] * r1s[h]) * lis[h];
  }
  if (t < 96) {
    int h = t / 12;
    op_l[t] = (p0[1168 + t] * r0s[h] + p1[1168 + t] * r1s[h]) * lis[h]
            - trans[i * 3 + (t % 3)];
  }
  __syncthreads();

  if (t < 96) {
    int c = t % 3, base = t - c;
    const float* R = rotm + (size_t)i * 9;
    float val = op_l[base] * R[c] + op_l[base + 1] * R[3 + c] + op_l[base + 2] * R[6 + c];
    rp_l[t] = val;
    frow[128 + t] = val;
  }
  __syncthreads();
  if (t < 32) {
    float x = rp_l[t * 3], y = rp_l[t * 3 + 1], z = rp_l[t * 3 + 2];
    frow[224 + t] = sqrtf(x * x + y * y + z * z + 1e-8f);
  }
}

// ---------------------------------------------------------------------------
// Kernel C1: k-split partial GEMM. grid (16, 8, 4)
// ---------------------------------------------------------------------------
__global__ __launch_bounds__(256) void k_outp(
    const float* __restrict__ feat, const float* __restrict__ Wout,
    float* __restrict__ ws)
{
  __shared__ float As[32 * 33];
  __shared__ float Bs[32 * 36];
  const int t = threadIdx.x;
  const int it = blockIdx.x, ot = blockIdx.y, z = blockIdx.z;
  const int row = t & 31, cb = (t >> 5) * 4;
  float4 acc = {0.f, 0.f, 0.f, 0.f};

  for (int kk = 0; kk < 10; ++kk) {
    int kt = z * 10 + kk;
    __syncthreads();
    #pragma unroll
    for (int q = 0; q < 4; ++q) {
      int f = t + q * 256; int r = f >> 5, c = f & 31;
      As[r * 33 + c] = feat[(size_t)(it * 32 + r) * 1280 + kt * 32 + c];
      Bs[r * 36 + c] = Wout[(size_t)(kt * 32 + r) * 256 + ot * 32 + c];
    }
    __syncthreads();
    #pragma unroll
    for (int k = 0; k < 32; ++k) {
      float a = As[row * 33 + k];
      float4 bv = *(const float4*)&Bs[k * 36 + cb];
      acc.x += a * bv.x; acc.y += a * bv.y; acc.z += a * bv.z; acc.w += a * bv.w;
    }
  }
  float* pc = ws + OFF_OUTP + (size_t)z * 131072;
  *(float4*)&pc[(size_t)(it * 32 + row) * 256 + ot * 32 + cb] = acc;
}

// ---------------------------------------------------------------------------
// Kernel C2: reduce partials + bias. grid 128 x 256.
// ---------------------------------------------------------------------------
__global__ __launch_bounds__(256) void k_outr(
    const float* __restrict__ ws, const float* __restrict__ bout,
    float* __restrict__ out)
{
  const int q = blockIdx.x * 256 + threadIdx.x;
  const float* pc = ws + OFF_OUTP;
  float4 a = *(const float4*)&pc[(size_t)q * 4];
  float4 b = *(const float4*)&pc[(size_t)q * 4 + 131072];
  float4 c = *(const float4*)&pc[(size_t)q * 4 + 262144];
  float4 d = *(const float4*)&pc[(size_t)q * 4 + 393216];
  float4 bias = *(const float4*)&bout[(q & 63) * 4];
  float4 r;
  r.x = a.x + b.x + c.x + d.x + bias.x;
  r.y = a.y + b.y + c.y + d.y + bias.y;
  r.z = a.z + b.z + c.z + d.z + bias.z;
  r.w = a.w + b.w + c.w + d.w + bias.w;
  *(float4*)&out[(size_t)q * 4] = r;
}

// ---------------------------------------------------------------------------
extern "C" void kernel_launch(void* const* d_in, const int* in_sizes, int n_in,
                              void* d_out, int out_size, void* d_ws, size_t ws_size,
                              hipStream_t stream) {
  const float* node  = (const float*)d_in[0];
  const float* edge  = (const float*)d_in[1];
  const float* rotm  = (const float*)d_in[2];
  const float* trans = (const float*)d_in[3];
  const float* Wsq   = (const float*)d_in[4];
  const float* Wsk   = (const float*)d_in[5];
  const float* Wsv   = (const float*)d_in[6];
  const float* Wpq   = (const float*)d_in[7];
  const float* Wpk   = (const float*)d_in[8];
  const float* Wpv   = (const float*)d_in[9];
  const float* pw    = (const float*)d_in[10];
  const float* Wpb   = (const float*)d_in[11];
  const float* bpb   = (const float*)d_in[12];
  const float* Wout  = (const float*)d_in[13];
  const float* bout  = (const float*)d_in[14];
  float* ws   = (float*)d_ws;
  float* out  = (float*)d_out;
  float* feat = ws + OFF_FEAT;
  __half* lg16 = (__half*)(ws + OFF_LG16);
  float* part = ws + OFF_PART;

  k_projgemm<<<dim3(16, 21), 256, 0, stream>>>(node, Wsq, Wsk, Wsv, Wpq, Wpk, Wpv, ws);
  k_rot2<<<128, 256, 0, stream>>>(rotm, trans, pw, bpb, ws);
  k_S<<<dim3(16, 16), 256, 0, stream>>>(ws, lg16);
  k_attnfused2<<<dim3(2, 512), 256, 0, stream>>>(edge, ws, lg16, Wpb, part);
  k_amerge<<<512, 256, 0, stream>>>(part, rotm, trans, feat);
  k_outp<<<dim3(16, 8, 4), 256, 0, stream>>>(feat, Wout, ws);
  k_outr<<<128, 256, 0, stream>>>(ws, bout, out);
}

// Round 12
// 116.160 us; speedup vs baseline: 3.1915x; 3.1915x over previous
//
#include <hip/hip_runtime.h>
#include <hip/hip_fp16.h>
#include <math.h>

#define NN 512
#define NODE_D 256
#define EDGE_D 128
#define HN 8

#define SCALAR_SCALE 0.14433756729740643f   // (3*16)^-0.5
#define POINT_SCALE  0.13608276348795434f   // (3*4*4.5)^-0.5
#define PAIR_SCALE   0.5773502691896258f    // 3^-0.5

// workspace float offsets
#define OFF_QS   0            // 512x128
#define OFF_KS   65536        // 512x128
#define OFF_VS   131072       // 512x128
#define OFF_VP   196608       // 512x96
#define OFF_QCAT 245760       // 512x288
#define OFF_KCAT 393216       // 512x288
#define OFF_FEAT 540672       // 512x1280
#define OFF_PRAW OFF_FEAT     // alias; consumed by k_rot2 before feat written
#define OFF_LG16 1196032      // 512*512*8 halfs = 1048576 float-equiv (4MB)
#define OFF_OUTP 2244608      // 4*512*256 floats
#define OFF_PART 2768896      // 512 i x 2 jc x 1280 floats (5.2MB)
// total ws = 4079616 floats = 16.3 MB

// Non-draining barrier: orders LDS producer->consumer (lgkmcnt) WITHOUT
// draining vmcnt — keeps global prefetch loads in flight across phases.
#define BARRIER_NODRAIN() do {                                   \
  __builtin_amdgcn_sched_barrier(0);                             \
  asm volatile("s_waitcnt lgkmcnt(0)\n\ts_barrier" ::: "memory");\
  __builtin_amdgcn_sched_barrier(0);                             \
} while (0)

// ---------------------------------------------------------------------------
// Kernel A1: Y(512x672) = node @ [Wsq|Wsk|Wsv|Wpq|Wpk|Wpv]. grid (16,21).
// ---------------------------------------------------------------------------
__global__ __launch_bounds__(256) void k_projgemm(
    const float* __restrict__ node,
    const float* __restrict__ Wsq, const float* __restrict__ Wsk, const float* __restrict__ Wsv,
    const float* __restrict__ Wpq, const float* __restrict__ Wpk, const float* __restrict__ Wpv,
    float* __restrict__ ws)
{
  __shared__ float As[32 * 33];
  __shared__ float Bs[32 * 36];
  const int t = threadIdx.x;
  const int it = blockIdx.x;
  const int ct = blockIdx.y;

  const float* W; int ncol, col0; float* dst; int ldd, dcol0;
  if (ct < 12) {
    int a = ct >> 2;
    W = (a == 0) ? Wsq : (a == 1) ? Wsk : Wsv;
    ncol = 128; col0 = (ct & 3) * 32;
    dst = ws + ((a == 0) ? OFF_QS : (a == 1) ? OFF_KS : OFF_VS);
    ldd = 128; dcol0 = col0;
  } else {
    int p = ct - 12;
    int a = p / 3, cc = p % 3;
    W = (a == 0) ? Wpq : (a == 1) ? Wpk : Wpv;
    ncol = 96; col0 = cc * 32;
    dst = ws + OFF_PRAW;
    ldd = 288; dcol0 = a * 96 + cc * 32;
  }

  const int row = t & 31, cb = (t >> 5) * 4;
  float4 acc = {0.f, 0.f, 0.f, 0.f};

  for (int kt = 0; kt < 8; ++kt) {
    __syncthreads();
    #pragma unroll
    for (int q = 0; q < 4; ++q) {
      int f = t + q * 256; int r = f >> 5, c = f & 31;
      As[r * 33 + c] = node[(size_t)(it * 32 + r) * 256 + kt * 32 + c];
      Bs[r * 36 + c] = W[(size_t)(kt * 32 + r) * ncol + col0 + c];
    }
    __syncthreads();
    #pragma unroll
    for (int k = 0; k < 32; ++k) {
      float a = As[row * 33 + k];
      float4 b = *(const float4*)&Bs[k * 36 + cb];
      acc.x += a * b.x; acc.y += a * b.y; acc.z += a * b.z; acc.w += a * b.w;
    }
  }
  *(float4*)&dst[(size_t)(it * 32 + row) * ldd + dcol0 + cb] = acc;
}

// ---------------------------------------------------------------------------
// Kernel A2: rotate/translate points; build Qcat/Kcat (scales folded); vp out.
// ---------------------------------------------------------------------------
__global__ __launch_bounds__(256) void k_rot2(
    const float* __restrict__ rotm, const float* __restrict__ trans,
    const float* __restrict__ pw_in, const float* __restrict__ bpb,
    float* __restrict__ ws)
{
  __shared__ float p_l[4][288];
  __shared__ float r_l[4][288];
  __shared__ float q2_l[4][8];
  __shared__ float k2_l[4][8];
  __shared__ float pw_l[8];
  __shared__ float bpb_l[8];
  const int t = threadIdx.x;
  const int n0 = blockIdx.x * 4;
  const float* praw = ws + OFF_PRAW;
  const float* qs_g = ws + OFF_QS;
  const float* ks_g = ws + OFF_KS;

  if (t < 8) {
    float x = pw_in[t];
    pw_l[t] = 0.5f * POINT_SCALE * logf(1.0f + expf(x));
    bpb_l[t] = bpb[t];
  }
  for (int idx = t; idx < 1152; idx += 256) {
    int row = idx / 288, rem = idx % 288;
    p_l[row][rem] = praw[(size_t)(n0 + row) * 288 + rem];
  }
  __syncthreads();

  for (int idx = t; idx < 1152; idx += 256) {
    int row = idx / 288, rem = idx % 288;
    int a = rem / 96, col = rem % 96;
    int rr = col % 3;
    int n = n0 + row;
    const float* R = rotm + (size_t)(n * 3 + rr) * 3;
    const float* P = &p_l[row][a * 96 + (col - rr)];
    float val = P[0] * R[0] + P[1] * R[1] + P[2] * R[2] + trans[n * 3 + rr];
    r_l[row][a * 96 + col] = val;
    if (a == 2) (ws + OFF_VP)[(size_t)n * 96 + col] = val;
  }
  __syncthreads();

  if (t < 64) {
    int row = t >> 4, rem = t & 15;
    int which = rem >> 3, h = rem & 7;
    const float* src = &r_l[row][which * 96 + h * 12];
    float s = 0.f;
    #pragma unroll
    for (int m = 0; m < 12; ++m) s += src[m] * src[m];
    if (which == 0) q2_l[row][h] = s; else k2_l[row][h] = s;
  }
  __syncthreads();

  for (int idx = t; idx < 2304; idx += 256) {
    int side = idx >= 1152;
    int per = idx - side * 1152;
    int row = per / 288, s = per % 288;
    int h = s / 36, e = s % 36;
    int n = n0 + row;
    float val;
    if (!side) {
      val = (e < 16) ? qs_g[(size_t)n * 128 + h * 16 + e] * SCALAR_SCALE
          : (e < 28) ? 2.0f * pw_l[h] * r_l[row][h * 12 + (e - 16)]
          : (e == 32) ? -pw_l[h]
          : (e == 33) ? (bpb_l[h] * PAIR_SCALE - pw_l[h] * q2_l[row][h])
          : 0.f;
      (ws + OFF_QCAT)[(size_t)n * 288 + s] = val;
    } else {
      val = (e < 16) ? ks_g[(size_t)n * 128 + h * 16 + e]
          : (e < 28) ? r_l[row][96 + h * 12 + (e - 16)]
          : (e == 32) ? k2_l[row][h]
          : (e == 33) ? 1.f
          : 0.f;
      (ws + OFF_KCAT)[(size_t)n * 288 + s] = val;
    }
  }
}

// ---------------------------------------------------------------------------
// Kernel B1: non-pair logits = batched GEMM lg[i,j,h] = dot36(Qcat,Kcat).
// ---------------------------------------------------------------------------
__global__ __launch_bounds__(256) void k_S(
    const float* __restrict__ ws_c, __half* __restrict__ lg16)
{
  __shared__ float4 Qt[32 * 36];
  __shared__ float4 Kt[32 * 37];
  __shared__ __half lgst[32 * 32 * 8];
  const int t = threadIdx.x;
  const int it = blockIdx.x, jt = blockIdx.y;
  const float* Qc = ws_c + OFF_QCAT;
  const float* Kc = ws_c + OFF_KCAT;
  const int ti = t >> 4, tj = t & 15;

  for (int hg = 0; hg < 2; ++hg) {
    __syncthreads();
    for (int f = t; f < 1152; f += 256) {
      int row = f / 36, c = f % 36;
      Qt[row * 36 + c] = *(const float4*)&Qc[(size_t)(it * 32 + row) * 288 + hg * 144 + c * 4];
      Kt[row * 37 + c] = *(const float4*)&Kc[(size_t)(jt * 32 + row) * 288 + hg * 144 + c * 4];
    }
    __syncthreads();

    float acc[2][2][4];
    #pragma unroll
    for (int a = 0; a < 2; ++a)
      #pragma unroll
      for (int b = 0; b < 2; ++b)
        #pragma unroll
        for (int h = 0; h < 4; ++h) acc[a][b][h] = 0.f;

    for (int c = 0; c < 9; ++c) {
      #pragma unroll
      for (int hh = 0; hh < 4; ++hh) {
        float4 q0 = Qt[(2 * ti + 0) * 36 + hh * 9 + c];
        float4 q1 = Qt[(2 * ti + 1) * 36 + hh * 9 + c];
        float4 k0 = Kt[(2 * tj + 0) * 37 + hh * 9 + c];
        float4 k1 = Kt[(2 * tj + 1) * 37 + hh * 9 + c];
        acc[0][0][hh] += q0.x * k0.x + q0.y * k0.y + q0.z * k0.z + q0.w * k0.w;
        acc[0][1][hh] += q0.x * k1.x + q0.y * k1.y + q0.z * k1.z + q0.w * k1.w;
        acc[1][0][hh] += q1.x * k0.x + q1.y * k0.y + q1.z * k0.z + q1.w * k0.w;
        acc[1][1][hh] += q1.x * k1.x + q1.y * k1.y + q1.z * k1.z + q1.w * k1.w;
      }
    }
    #pragma unroll
    for (int a = 0; a < 2; ++a)
      #pragma unroll
      for (int b = 0; b < 2; ++b)
        #pragma unroll
        for (int hh = 0; hh < 4; ++hh)
          lgst[((2 * ti + a) * 32 + (2 * tj + b)) * 8 + hg * 4 + hh] = __float2half(acc[a][b][hh]);
  }
  __syncthreads();

  for (int f = t; f < 1024; f += 256) {
    int il = f >> 5, jl = f & 31;
    float4 v = *(const float4*)&lgst[(il * 32 + jl) * 8];
    *(float4*)&lg16[((size_t)(it * 32 + il) * 512 + jt * 32 + jl) * 8] = v;
  }
}

// ---------------------------------------------------------------------------
// Kernel B2: flash-style fused attention, j-split. grid (2 jc, 512 i).
// Non-draining barriers keep global prefetch in flight across phases.
// NOTE: plain __launch_bounds__(256) — forcing 4 waves/EU capped VGPR at 64
// and spilled the ~120-reg working set to scratch (R11: FETCH 69.5->796 GB).
// ---------------------------------------------------------------------------
static __device__ inline __half2 shfl_xor_h2(__half2 h, int m) {
  int v = __builtin_bit_cast(int, h);
  v = __shfl_xor(v, m);
  return __builtin_bit_cast(__half2, v);
}

__global__ __launch_bounds__(256) void k_attnfused2(
    const float* __restrict__ edge, const float* __restrict__ ws_r,
    const __half* __restrict__ lg16, const float* __restrict__ Wpb,
    float* __restrict__ part)
{
  __shared__ float e_l[2][32][132];    // 33.8 KB (epilogue reuses as pl[4][8][132])
  __shared__ float w_t2[32][8];        // transposed: [j][h], b128 broadcast reads
  __shared__ __half2 lg_th[32][5];     // phase-L pair logits (half2 x4 used)
  __shared__ float mh[8], sh[8], resc[8];
  __shared__ float vsp[4 * 128];
  __shared__ float vpp[4 * 96];

  const int t = threadIdx.x;
  const int jc = blockIdx.x;           // j-chunk 0/1
  const int i  = blockIdx.y;
  const int dq = t & 31, jg = t >> 5;  // phase A mapping
  const int sub = t & 15;              // phase L mapping
  const int hv = dq >> 2;
  const int hp = (dq < 24) ? (dq / 3) : 0;

  const float* eb  = edge + ((size_t)i * 512 + jc * 256) * 128;
  const float* vsg = ws_r + OFF_VS + (size_t)jc * 256 * 128;
  const float* vpg = ws_r + OFF_VP + (size_t)jc * 256 * 96;
  const __half* lgb = lg16 + ((size_t)i * 512 + jc * 256) * 8;

  // per-thread Wpb slice for d = sub*8 + dd (PAIR_SCALE folded)
  float wv[8][8];
  #pragma unroll
  for (int dd = 0; dd < 8; ++dd)
    #pragma unroll
    for (int h = 0; h < 8; ++h)
      wv[dd][h] = Wpb[(size_t)(sub * 8 + dd) * 8 + h] * PAIR_SCALE;

  if (t < 8) { mh[t] = -1e30f; sh[t] = 0.f; }

  float4 accp[8];
  #pragma unroll
  for (int h = 0; h < 8; ++h) accp[h] = {0.f, 0.f, 0.f, 0.f};
  float4 accv = {0.f, 0.f, 0.f, 0.f};
  float4 accw = {0.f, 0.f, 0.f, 0.f};

  // stage tile 0 (32 rows x 512B, fully coalesced)
  #pragma unroll
  for (int p = 0; p < 4; ++p) {
    int f = p * 256 + t, r = f >> 5, g = f & 31;
    *(float4*)&e_l[0][r][g * 4] = *(const float4*)&eb[(size_t)r * 128 + g * 4];
  }
  __syncthreads();   // tile0 staged (full drain ok once)

  int cur = 0;
  for (int tile = 0; tile < 8; ++tile) {
    // prefetch for phase S FIRST (so its use waits at vmcnt(4), leaving nxt in flight)
    __half lgh = lgb[(size_t)(tile * 32 + (t & 31)) * 8 + (t >> 5)];
    // prefetch next tile into registers (T14); retires under phases L/S/A
    float4 nxt0, nxt1, nxt2, nxt3;
    if (tile < 7) {
      const float* ebn = eb + (size_t)(tile + 1) * 32 * 128;
      { int f = t;       int r = f >> 5, g = f & 31; nxt0 = *(const float4*)&ebn[(size_t)r * 128 + g * 4]; }
      { int f = 256 + t; int r = f >> 5, g = f & 31; nxt1 = *(const float4*)&ebn[(size_t)r * 128 + g * 4]; }
      { int f = 512 + t; int r = f >> 5, g = f & 31; nxt2 = *(const float4*)&ebn[(size_t)r * 128 + g * 4]; }
      { int f = 768 + t; int r = f >> 5, g = f & 31; nxt3 = *(const float4*)&ebn[(size_t)r * 128 + g * 4]; }
    }

    // ---- phase L: pair logits, 2 passes x 16 rows; thread (jrow, sub) ----
    #pragma unroll
    for (int pass = 0; pass < 2; ++pass) {
      const int jrow = (t >> 4) + pass * 16;
      float p8[8] = {0, 0, 0, 0, 0, 0, 0, 0};
      #pragma unroll
      for (int k = 0; k < 2; ++k) {
        float4 e = *(float4*)&e_l[cur][jrow][(sub * 2 + k) * 4];
        #pragma unroll
        for (int h = 0; h < 8; ++h)
          p8[h] += e.x * wv[k * 4 + 0][h] + e.y * wv[k * 4 + 1][h]
                 + e.z * wv[k * 4 + 2][h] + e.w * wv[k * 4 + 3][h];
      }
      // pack to half2, 16-lane butterfly (k_pair's proven scheme)
      __half2 h0 = __floats2half2_rn(p8[0], p8[1]);
      __half2 h1 = __floats2half2_rn(p8[2], p8[3]);
      __half2 h2 = __floats2half2_rn(p8[4], p8[5]);
      __half2 h3 = __floats2half2_rn(p8[6], p8[7]);
      #pragma unroll
      for (int m = 1; m <= 8; m <<= 1) {
        h0 = __hadd2(h0, shfl_xor_h2(h0, m));
        h1 = __hadd2(h1, shfl_xor_h2(h1, m));
        h2 = __hadd2(h2, shfl_xor_h2(h2, m));
        h3 = __hadd2(h3, shfl_xor_h2(h3, m));
      }
      if (sub == 0) {
        lg_th[jrow][0] = h0; lg_th[jrow][1] = h1;
        lg_th[jrow][2] = h2; lg_th[jrow][3] = h3;
      }
    }
    BARRIER_NODRAIN();   // lg_th visible; nxt/lgh loads stay in flight

    // ---- phase S: online softmax, full block (h = t>>5, jS = t&31) ----
    {
      const int hS = t >> 5, jS = t & 31;
      __half2 ph = lg_th[jS][hS >> 1];
      float pv = (hS & 1) ? __high2float(ph) : __low2float(ph);
      float x = pv + __half2float(lgh);
      float mt = x;
      #pragma unroll
      for (int s = 16; s; s >>= 1) mt = fmaxf(mt, __shfl_xor(mt, s));
      float mo = mh[hS];
      float mn = fmaxf(mo, mt);
      float w = __expf(x - mn);
      float sw = w;
      #pragma unroll
      for (int s = 16; s; s >>= 1) sw += __shfl_xor(sw, s);
      w_t2[jS][hS] = w;
      if (jS == 0) {
        float r = __expf(mo - mn);
        resc[hS] = r;
        mh[hS] = mn;
        sh[hS] = sh[hS] * r + sw;
      }
    }
    BARRIER_NODRAIN();   // w_t2/resc/mh/sh visible

    // ---- phase A: rescale + accumulate; thread (dq, jg) owns 4 rows ----
    {
      #pragma unroll
      for (int h = 0; h < 8; ++h) {
        float r = resc[h];
        accp[h].x *= r; accp[h].y *= r; accp[h].z *= r; accp[h].w *= r;
      }
      {
        float rv = resc[hv];
        accv.x *= rv; accv.y *= rv; accv.z *= rv; accv.w *= rv;
      }
      if (dq < 24) {
        float rp = resc[hp];
        accw.x *= rp; accw.y *= rp; accw.z *= rp; accw.w *= rp;
      }
      #pragma unroll
      for (int jj = 0; jj < 4; ++jj) {
        const int j = jg * 4 + jj;
        float4 e = *(float4*)&e_l[cur][j][dq * 4];
        float4 wlo = *(float4*)&w_t2[j][0];   // broadcast b128
        float4 whi = *(float4*)&w_t2[j][4];
        accp[0].x += wlo.x * e.x; accp[0].y += wlo.x * e.y; accp[0].z += wlo.x * e.z; accp[0].w += wlo.x * e.w;
        accp[1].x += wlo.y * e.x; accp[1].y += wlo.y * e.y; accp[1].z += wlo.y * e.z; accp[1].w += wlo.y * e.w;
        accp[2].x += wlo.z * e.x; accp[2].y += wlo.z * e.y; accp[2].z += wlo.z * e.z; accp[2].w += wlo.z * e.w;
        accp[3].x += wlo.w * e.x; accp[3].y += wlo.w * e.y; accp[3].z += wlo.w * e.z; accp[3].w += wlo.w * e.w;
        accp[4].x += whi.x * e.x; accp[4].y += whi.x * e.y; accp[4].z += whi.x * e.z; accp[4].w += whi.x * e.w;
        accp[5].x += whi.y * e.x; accp[5].y += whi.y * e.y; accp[5].z += whi.y * e.z; accp[5].w += whi.y * e.w;
        accp[6].x += whi.z * e.x; accp[6].y += whi.z * e.y; accp[6].z += whi.z * e.z; accp[6].w += whi.z * e.w;
        accp[7].x += whi.w * e.x; accp[7].y += whi.w * e.y; accp[7].z += whi.w * e.z; accp[7].w += whi.w * e.w;

        const int gj = tile * 32 + j;
        float4 v = *(const float4*)&vsg[(size_t)gj * 128 + dq * 4];
        float wvv = w_t2[j][hv];             // direct LDS read (no dyn reg index)
        accv.x += wvv * v.x; accv.y += wvv * v.y;
        accv.z += wvv * v.z; accv.w += wvv * v.w;
        if (dq < 24) {
          float4 pv4 = *(const float4*)&vpg[(size_t)gj * 96 + dq * 4];
          float wpp = w_t2[j][hp];
          accw.x += wpp * pv4.x; accw.y += wpp * pv4.y;
          accw.z += wpp * pv4.z; accw.w += wpp * pv4.w;
        }
      }
    }
    BARRIER_NODRAIN();   // phase-A w_t2 reads done before next phase S rewrite

    if (tile < 7) {
      // compiler inserts vmcnt waits on nxt registers here automatically
      { int f = t;       int r = f >> 5, g = f & 31; *(float4*)&e_l[cur ^ 1][r][g * 4] = nxt0; }
      { int f = 256 + t; int r = f >> 5, g = f & 31; *(float4*)&e_l[cur ^ 1][r][g * 4] = nxt1; }
      { int f = 512 + t; int r = f >> 5, g = f & 31; *(float4*)&e_l[cur ^ 1][r][g * 4] = nxt2; }
      { int f = 768 + t; int r = f >> 5, g = f & 31; *(float4*)&e_l[cur ^ 1][r][g * 4] = nxt3; }
      cur ^= 1;
      BARRIER_NODRAIN(); // new tile visible before next phase L
    }
  }

  // ---- epilogue: combine jg pairs in-wave, reduce 4 waves via LDS ----
  #pragma unroll
  for (int h = 0; h < 8; ++h) {
    accp[h].x += __shfl_xor(accp[h].x, 32);
    accp[h].y += __shfl_xor(accp[h].y, 32);
    accp[h].z += __shfl_xor(accp[h].z, 32);
    accp[h].w += __shfl_xor(accp[h].w, 32);
  }
  accv.x += __shfl_xor(accv.x, 32); accv.y += __shfl_xor(accv.y, 32);
  accv.z += __shfl_xor(accv.z, 32); accv.w += __shfl_xor(accv.w, 32);
  accw.x += __shfl_xor(accw.x, 32); accw.y += __shfl_xor(accw.y, 32);
  accw.z += __shfl_xor(accw.z, 32); accw.w += __shfl_xor(accw.w, 32);

  __syncthreads();   // all e_l reads done before reuse as pl (full drain fine here)

  const int wid = t >> 6;
  float* pl = (float*)e_l;   // reuse as [4][8][132]
  if ((t & 63) < 32) {
    #pragma unroll
    for (int h = 0; h < 8; ++h)
      *(float4*)&pl[(size_t)(wid * 8 + h) * 132 + dq * 4] = accp[h];
    *(float4*)&vsp[wid * 128 + dq * 4] = accv;
    if (dq < 24) *(float4*)&vpp[wid * 96 + dq * 4] = accw;
  }
  __syncthreads();

  float* pp = part + ((size_t)i * 2 + jc) * 1280;
  if (t < 8) { pp[t] = mh[t]; pp[8 + t] = sh[t]; }
  {
    const int h = t >> 5, d4 = (t & 31) * 4;
    float4 s = {0.f, 0.f, 0.f, 0.f};
    #pragma unroll
    for (int q = 0; q < 4; ++q) {
      float4 v = *(float4*)&pl[(size_t)(q * 8 + h) * 132 + d4];
      s.x += v.x; s.y += v.y; s.z += v.z; s.w += v.w;
    }
    *(float4*)&pp[16 + h * 128 + d4] = s;
  }
  if (t < 128)
    pp[1040 + t] = vsp[t] + vsp[128 + t] + vsp[256 + t] + vsp[384 + t];
  if (t < 96)
    pp[1168 + t] = vpp[t] + vpp[96 + t] + vpp[192 + t] + vpp[288 + t];
}

// ---------------------------------------------------------------------------
// Kernel B3: merge the 2 j-chunk partials, normalize, rotation/norm epilogue.
// ---------------------------------------------------------------------------
__global__ __launch_bounds__(256) void k_amerge(
    const float* __restrict__ part, const float* __restrict__ rotm,
    const float* __restrict__ trans, float* __restrict__ feat)
{
  __shared__ float r0s[8], r1s[8], lis[8];
  __shared__ float op_l[96], rp_l[96];
  const int t = threadIdx.x, i = blockIdx.x;
  const float* p0 = part + (size_t)i * 2560;
  const float* p1 = p0 + 1280;

  if (t < 8) {
    float m0 = p0[t], m1 = p1[t];
    float M = fmaxf(m0, m1);
    float r0 = __expf(m0 - M), r1 = __expf(m1 - M);
    float S = p0[8 + t] * r0 + p1[8 + t] * r1;
    r0s[t] = r0; r1s[t] = r1; lis[t] = 1.0f / S;
  }
  __syncthreads();

  float* frow = feat + (size_t)i * 1280;
  {
    const int h = t >> 5, d4 = (t & 31) * 4;
    float4 a = *(const float4*)&p0[16 + h * 128 + d4];
    float4 b = *(const float4*)&p1[16 + h * 128 + d4];
    float r0 = r0s[h], r1 = r1s[h], li = lis[h];
    float4 o;
    o.x = (a.x * r0 + b.x * r1) * li;
    o.y = (a.y * r0 + b.y * r1) * li;
    o.z = (a.z * r0 + b.z * r1) * li;
    o.w = (a.w * r0 + b.w * r1) * li;
    *(float4*)&frow[256 + h * 128 + d4] = o;
  }
  if (t < 128) {
    int h = t >> 4;
    frow[t] = (p0[1040 + t] * r0s[h] + p1[1040 + t] * r1s[h]) * lis[h];
  }
  if (t < 96) {
    int h = t / 12;
    op_l[t] = (p0[1168 + t] * r0s[h] + p1[1168 + t] * r1s[h]) * lis[h]
            - trans[i * 3 + (t % 3)];
  }
  __syncthreads();

  if (t < 96) {
    int c = t % 3, base = t - c;
    const float* R = rotm + (size_t)i * 9;
    float val = op_l[base] * R[c] + op_l[base + 1] * R[3 + c] + op_l[base + 2] * R[6 + c];
    rp_l[t] = val;
    frow[128 + t] = val;
  }
  __syncthreads();
  if (t < 32) {
    float x = rp_l[t * 3], y = rp_l[t * 3 + 1], z = rp_l[t * 3 + 2];
    frow[224 + t] = sqrtf(x * x + y * y + z * z + 1e-8f);
  }
}

// ---------------------------------------------------------------------------
// Kernel C1: k-split partial GEMM. grid (16, 8, 4)
// ---------------------------------------------------------------------------
__global__ __launch_bounds__(256) void k_outp(
    const float* __restrict__ feat, const float* __restrict__ Wout,
    float* __restrict__ ws)
{
  __shared__ float As[32 * 33];
  __shared__ float Bs[32 * 36];
  const int t = threadIdx.x;
  const int it = blockIdx.x, ot = blockIdx.y, z = blockIdx.z;
  const int row = t & 31, cb = (t >> 5) * 4;
  float4 acc = {0.f, 0.f, 0.f, 0.f};

  for (int kk = 0; kk < 10; ++kk) {
    int kt = z * 10 + kk;
    __syncthreads();
    #pragma unroll
    for (int q = 0; q < 4; ++q) {
      int f = t + q * 256; int r = f >> 5, c = f & 31;
      As[r * 33 + c] = feat[(size_t)(it * 32 + r) * 1280 + kt * 32 + c];
      Bs[r * 36 + c] = Wout[(size_t)(kt * 32 + r) * 256 + ot * 32 + c];
    }
    __syncthreads();
    #pragma unroll
    for (int k = 0; k < 32; ++k) {
      float a = As[row * 33 + k];
      float4 bv = *(const float4*)&Bs[k * 36 + cb];
      acc.x += a * bv.x; acc.y += a * bv.y; acc.z += a * bv.z; acc.w += a * bv.w;
    }
  }
  float* pc = ws + OFF_OUTP + (size_t)z * 131072;
  *(float4*)&pc[(size_t)(it * 32 + row) * 256 + ot * 32 + cb] = acc;
}

// ---------------------------------------------------------------------------
// Kernel C2: reduce partials + bias. grid 128 x 256.
// ---------------------------------------------------------------------------
__global__ __launch_bounds__(256) void k_outr(
    const float* __restrict__ ws, const float* __restrict__ bout,
    float* __restrict__ out)
{
  const int q = blockIdx.x * 256 + threadIdx.x;
  const float* pc = ws + OFF_OUTP;
  float4 a = *(const float4*)&pc[(size_t)q * 4];
  float4 b = *(const float4*)&pc[(size_t)q * 4 + 131072];
  float4 c = *(const float4*)&pc[(size_t)q * 4 + 262144];
  float4 d = *(const float4*)&pc[(size_t)q * 4 + 393216];
  float4 bias = *(const float4*)&bout[(q & 63) * 4];
  float4 r;
  r.x = a.x + b.x + c.x + d.x + bias.x;
  r.y = a.y + b.y + c.y + d.y + bias.y;
  r.z = a.z + b.z + c.z + d.z + bias.z;
  r.w = a.w + b.w + c.w + d.w + bias.w;
  *(float4*)&out[(size_t)q * 4] = r;
}

// ---------------------------------------------------------------------------
extern "C" void kernel_launch(void* const* d_in, const int* in_sizes, int n_in,
                              void* d_out, int out_size, void* d_ws, size_t ws_size,
                              hipStream_t stream) {
  const float* node  = (const float*)d_in[0];
  const float* edge  = (const float*)d_in[1];
  const float* rotm  = (const float*)d_in[2];
  const float* trans = (const float*)d_in[3];
  const float* Wsq   = (const float*)d_in[4];
  const float* Wsk   = (const float*)d_in[5];
  const float* Wsv   = (const float*)d_in[6];
  const float* Wpq   = (const float*)d_in[7];
  const float* Wpk   = (const float*)d_in[8];
  const float* Wpv   = (const float*)d_in[9];
  const float* pw    = (const float*)d_in[10];
  const float* Wpb   = (const float*)d_in[11];
  const float* bpb   = (const float*)d_in[12];
  const float* Wout  = (const float*)d_in[13];
  const float* bout  = (const float*)d_in[14];
  float* ws   = (float*)d_ws;
  float* out  = (float*)d_out;
  float* feat = ws + OFF_FEAT;
  __half* lg16 = (__half*)(ws + OFF_LG16);
  float* part = ws + OFF_PART;

  k_projgemm<<<dim3(16, 21), 256, 0, stream>>>(node, Wsq, Wsk, Wsv, Wpq, Wpk, Wpv, ws);
  k_rot2<<<128, 256, 0, stream>>>(rotm, trans, pw, bpb, ws);
  k_S<<<dim3(16, 16), 256, 0, stream>>>(ws, lg16);
  k_attnfused2<<<dim3(2, 512), 256, 0, stream>>>(edge, ws, lg16, Wpb, part);
  k_amerge<<<512, 256, 0, stream>>>(part, rotm, trans, feat);
  k_outp<<<dim3(16, 8, 4), 256, 0, stream>>>(feat, Wout, ws);
  k_outr<<<128, 256, 0, stream>>>(ws, bout, out);
}